// Round 2
// baseline (636.515 us; speedup 1.0000x reference)
//
#include <hip/hip_runtime.h>
#include <cfloat>

// Problem: B=2, M=8, I=128, J=64, DIM=512, HEADS=8, DH=64, INNER=512.
// R = B*M*I = 2048 independent "query rows"; each attends over its own 64
// memory slots (mems row block [64][512]).
//
// Algebraic refactor (J << DIM):
//   sim[r,h,j] = sum_e mems[r,j,e] * T[r,h,e],  T[r,h,e] = sum_d Q[r,h,d]*Wk[e,h*64+d]
//   out        = (sum_j attn[r,h,j]*mems[r,j,:]) @ Wv_h  @ Wo + bo
// => avoids materializing K/V; total ~6.4 GF fp32, memory-bound on the single
//    256 MB pass over mems (~41 us floor at 6.3 TB/s).
//
// ws layout (fp32): Q[2048][512] | T[2048][4096] | cbar[2048][4096] | O[2048][512]
//                   | Wkt[512][512]  = 73 MB total.

#define SCALE 0.125f

// ---------------------------------------------------------------------------
// Generic skinny GEMM, "column-per-lane" (no LDS):
//   C[r0+i][t] = alpha * sum_e A[r0+i][hoff+e] * B[e*ldb + bcol0 + t] (+ bias)
// A wave-uniform -> s_load; B rows coalesced across lanes (L2-resident).
// ---------------------------------------------------------------------------
__global__ __launch_bounds__(512) void k_clrb(
    const float* __restrict__ A, int lda, int a_hs,
    const float* __restrict__ B, int ldb, int bcol0,
    const float* __restrict__ bias, float alpha,
    float* __restrict__ C, int ldc, int K)
{
  const int t  = threadIdx.x;           // output column (0..511)
  const int r0 = blockIdx.x * 8;
  int hoff = 0;
  if (a_hs) hoff = __builtin_amdgcn_readfirstlane(t >> 6) * a_hs; // head = wave
  const float* a0 = A + (size_t)r0 * lda + hoff;
  const float* bp = B + bcol0 + t;
  float acc[8];
#pragma unroll
  for (int i = 0; i < 8; ++i) acc[i] = 0.f;
  for (int e = 0; e < K; e += 8) {
#pragma unroll
    for (int ee = 0; ee < 8; ++ee) {
      float bv = bp[(size_t)(e + ee) * ldb];          // coalesced across lanes
#pragma unroll
      for (int i = 0; i < 8; ++i)
        acc[i] += a0[(size_t)i * lda + e + ee] * bv;  // uniform -> s_load
    }
  }
  float bb = bias ? bias[t] : 0.f;
#pragma unroll
  for (int i = 0; i < 8; ++i)
    C[(size_t)(r0 + i) * ldc + t] = acc[i] * alpha + bb;
}

// ---------------------------------------------------------------------------
// Wkt[c][f] = Wkv[f][c] for c in [0,512)  (K-half only). 64x64 LDS tiles.
// Makes k_tmat's B reads lane-coalesced (was a 64-line scatter per load).
// ---------------------------------------------------------------------------
__global__ __launch_bounds__(256) void k_transpose(
    const float* __restrict__ Wkv, float* __restrict__ Wkt)
{
  __shared__ float tile[64][65];
  const int lx = threadIdx.x & 63;
  const int ly = threadIdx.x >> 6;          // 0..3
  const int bx = blockIdx.x;                // c-tile
  const int by = blockIdx.y;                // f-tile
#pragma unroll
  for (int i = 0; i < 16; ++i) {
    const int y = ly + i * 4;               // 0..63
    tile[y][lx] = Wkv[(size_t)(by * 64 + y) * 1024 + bx * 64 + lx];
  }
  __syncthreads();
#pragma unroll
  for (int i = 0; i < 16; ++i) {
    const int y = ly + i * 4;
    Wkt[(size_t)(bx * 64 + y) * 512 + by * 64 + lx] = tile[lx][y];
  }
}

// ---------------------------------------------------------------------------
// T[r][h*512+e] = sum_d Q[r][h*64+d] * Wkt[h*64+d][e]   (K=64)
// B reads lane-coalesced; 128 KB head-slice L2-hot across all r-blocks.
// ---------------------------------------------------------------------------
__global__ __launch_bounds__(512) void k_tmat(
    const float* __restrict__ Q, const float* __restrict__ Wkt,
    float* __restrict__ T)
{
  const int e  = threadIdx.x;
  const int r0 = blockIdx.x * 8;
  const int h  = blockIdx.y;
  const float* q0 = Q + (size_t)r0 * 512 + h * 64;       // uniform -> s_load
  const float* bp = Wkt + (size_t)h * 64 * 512 + e;      // lane-coalesced rows
  float acc[8];
#pragma unroll
  for (int i = 0; i < 8; ++i) acc[i] = 0.f;
#pragma unroll
  for (int d = 0; d < 64; ++d) {
    float bv = bp[(size_t)d * 512];
#pragma unroll
    for (int i = 0; i < 8; ++i) acc[i] += q0[(size_t)i * 512 + d] * bv;
  }
  float* o = T + (size_t)r0 * 4096 + h * 512 + e;
#pragma unroll
  for (int i = 0; i < 8; ++i) o[(size_t)i * 4096] = acc[i];
}

// ---------------------------------------------------------------------------
// K2: per row r -- sim = mems_row @ T_row^T, mask, softmax(j), cbar = attn @ m.
// 1024 threads = 16 waves, ONE pass over mems. Thread (j=t&63, cs=t>>6) holds
// mems[r][j][cs*32..+32) in 8 float4 = 32 VGPRs (total ~80, no spill at the
// 128-VGPR cap from __launch_bounds__(1024,4)). cbar goes through a padded LDS
// tile in 2 column phases; row stride 260 floats (260/4=65 odd -> b128 rows
// land on distinct 16B bank-groups, conflict-free).  LDS 101 KB, 1 block/CU.
// ---------------------------------------------------------------------------
__global__ __launch_bounds__(1024, 4) void k_attn(
    const float* __restrict__ mems, const float* __restrict__ Tm,
    const int* __restrict__ mask, float* __restrict__ cbar)
{
  __shared__ float sm[16640 + 8192 + 512];
  float* m_q  = sm;                 // [64][260] phase tile (66.5 KB)
  float* part = sm + 16640;         // sim partials [16][8][64] / cbar [4][8][256]
  float* p_s  = sm + 16640 + 8192;  // attn weights [64 j][8 h]

  const int t   = threadIdx.x;
  const int r   = blockIdx.x;
  const int j   = t & 63;
  const int cs  = t >> 6;                                  // 0..15
  const int csu = __builtin_amdgcn_readfirstlane(cs);

  // ---- stage this thread's 32-float slice of the mems row block into regs
  const float4* mrow =
      (const float4*)(mems + ((size_t)r * 64 + j) * 512 + cs * 32);
  float4 mr[8];
#pragma unroll
  for (int i = 0; i < 8; ++i) mr[i] = mrow[i];

  // ---- sim partials over this thread's c-slice (T via wave-uniform s_loads)
  const float* Trow = Tm + (size_t)r * 4096 + csu * 32;
  float acc[8];
#pragma unroll
  for (int h = 0; h < 8; ++h) acc[h] = 0.f;
#pragma unroll
  for (int i = 0; i < 8; ++i) {
    float4 mv = mr[i];
#pragma unroll
    for (int h = 0; h < 8; ++h) {
      float4 tv = *(const float4*)(Trow + h * 512 + i * 4);
      acc[h] += mv.x * tv.x + mv.y * tv.y + mv.z * tv.z + mv.w * tv.w;
    }
  }
#pragma unroll
  for (int h = 0; h < 8; ++h) part[cs * 512 + h * 64 + j] = acc[h];
  __syncthreads();

  // ---- reduce 16 c-segment partials; mask; per-head softmax (wave h, lane j)
  if (t < 512) {
    const int h = cs & 7;
    float s = 0.f;
#pragma unroll
    for (int c2 = 0; c2 < 16; ++c2) s += part[c2 * 512 + h * 64 + j];
    const bool mk = mask[(size_t)r * 64 + j] != 0;
    s = mk ? s : -FLT_MAX;
    float mx = s;
#pragma unroll
    for (int o = 32; o > 0; o >>= 1) mx = fmaxf(mx, __shfl_xor(mx, o));
    float ev = mk ? __expf(s - mx) : 0.f;
    float l = ev;
#pragma unroll
    for (int o = 32; o > 0; o >>= 1) l += __shfl_xor(l, o);
    p_s[j * 8 + h] = ev / l;
  }
  __syncthreads();

  // ---- cbar[h][c] = sum_j p[h][j]*m[j][c], 2 phases of 256 columns
  const int cc = t & 255;
  const int jh = t >> 8;                       // j-group 0..3 (16 j's each)
  for (int q = 0; q < 2; ++q) {
    if ((cs >> 3) == q) {                      // this thread's slice is in phase q
      float* dst = m_q + j * 260 + (cs & 7) * 32;
#pragma unroll
      for (int i = 0; i < 8; ++i) *(float4*)(dst + i * 4) = mr[i];
    }
    __syncthreads();                           // m_q ready
    float cb[8];
#pragma unroll
    for (int h = 0; h < 8; ++h) cb[h] = 0.f;
#pragma unroll
    for (int k = 0; k < 16; ++k) {
      const int jj = jh * 16 + k;
      float  mv = m_q[jj * 260 + cc];          // lanes consecutive-c: free
      float4 pa = *(const float4*)(p_s + jj * 8);      // uniform -> broadcast
      float4 pb = *(const float4*)(p_s + jj * 8 + 4);
      cb[0] += pa.x * mv; cb[1] += pa.y * mv; cb[2] += pa.z * mv; cb[3] += pa.w * mv;
      cb[4] += pb.x * mv; cb[5] += pb.y * mv; cb[6] += pb.z * mv; cb[7] += pb.w * mv;
    }
#pragma unroll
    for (int h = 0; h < 8; ++h) part[(jh * 8 + h) * 256 + cc] = cb[h];
    __syncthreads();                           // partials ready
#pragma unroll
    for (int w = 0; w < 2; ++w) {
      const int idx = t + w * 1024;
      const int h   = idx >> 8;
      const int c2  = idx & 255;
      float v = part[(0 * 8 + h) * 256 + c2] + part[(1 * 8 + h) * 256 + c2] +
                part[(2 * 8 + h) * 256 + c2] + part[(3 * 8 + h) * 256 + c2];
      cbar[(size_t)r * 4096 + h * 512 + q * 256 + c2] = v;
    }
    __syncthreads();                           // before next phase reuses LDS
  }
}

// ---------------------------------------------------------------------------
extern "C" void kernel_launch(void* const* d_in, const int* in_sizes, int n_in,
                              void* d_out, int out_size, void* d_ws, size_t ws_size,
                              hipStream_t stream)
{
  const float* x    = (const float*)d_in[0];   // [2048][512]
  const float* mems = (const float*)d_in[1];   // [2048][64][512]
  const int*   mask = (const int*)  d_in[2];   // [2048][64]
  const float* Wq   = (const float*)d_in[3];   // [512][512]
  const float* Wkv  = (const float*)d_in[4];   // [512][1024] (k | v)
  const float* Wo   = (const float*)d_in[5];   // [512][512]
  const float* bo   = (const float*)d_in[6];   // [512]
  float* out = (float*)d_out;                  // [2048][512]

  float* Q   = (float*)d_ws;                   // 2048*512
  float* Tm  = Q   + (size_t)2048 * 512;       // 2048*4096
  float* cb  = Tm  + (size_t)2048 * 4096;      // 2048*4096
  float* O   = cb  + (size_t)2048 * 4096;      // 2048*512
  float* Wkt = O   + (size_t)2048 * 512;       // 512*512

  // Wkt = transpose of K-half of Wkv  (fixes k_tmat's 64-line scatter loads)
  k_transpose<<<dim3(8, 8), 256, 0, stream>>>(Wkv, Wkt);
  // Q = SCALE * X @ Wq
  k_clrb<<<256, 512, 0, stream>>>(x, 512, 0, Wq, 512, 0, nullptr, SCALE, Q, 512, 512);
  // T[r][h][e] = sum_d Q[r][h*64+d] * Wkt[h*64+d][e]
  k_tmat<<<dim3(256, 8), 512, 0, stream>>>(Q, Wkt, Tm);
  // fused sim -> mask -> softmax -> cbar (single pass over mems)
  k_attn<<<2048, 1024, 0, stream>>>(mems, Tm, mask, cb);
  // O[r][h*64+d] = sum_e cbar[r][h*512+e] * Wkv[e][512 + h*64+d]
  k_clrb<<<256, 512, 0, stream>>>(cb, 4096, 512, Wkv, 1024, 512, nullptr, 1.f, O, 512, 512);
  // out = O @ Wo + bo
  k_clrb<<<256, 512, 0, stream>>>(O, 512, 0, Wo, 512, 0, bo, 1.f, out, 512, 512);
}